// Round 1
// baseline (431.033 us; speedup 1.0000x reference)
//
#include <hip/hip_runtime.h>

#define XDIM 512
#define CDIM 32
#define NPIX (XDIM * XDIM)

// ---------------------------------------------------------------------------
// Kernel A: batch-independent bilinear feature image.
// feats[p*32+c] = bilinear(data) at precomputed integer corners/weights.
// One thread per (pixel, channel): lanes 0..31 of each 32-thread group share a
// pixel -> coalesced 128B reads of data rows.
// ---------------------------------------------------------------------------
__global__ __launch_bounds__(256) void feats_kernel(
    const float* __restrict__ data, const float* __restrict__ lerp_w,
    const int* __restrict__ x0, const int* __restrict__ y0,
    const int* __restrict__ x1, const int* __restrict__ y1,
    float* __restrict__ feats)
{
    int tid = blockIdx.x * 256 + threadIdx.x;
    int p = tid >> 5;   // pixel index
    int c = tid & 31;   // channel
    if (p >= NPIX) return;
    float wA = lerp_w[p * 2 + 0];
    float wB = lerp_w[p * 2 + 1];
    int xa = x0[p], ya = y0[p], xb = x1[p], yb = y1[p];
    float v00 = data[(ya * XDIM + xa) * CDIM + c];
    float v01 = data[(ya * XDIM + xb) * CDIM + c];
    float v10 = data[(yb * XDIM + xa) * CDIM + c];
    float v11 = data[(yb * XDIM + xb) * CDIM + c];
    float r = v00 * (1.f - wA) * (1.f - wB)
            + v01 * wA * (1.f - wB)
            + v10 * (1.f - wA) * wB
            + v11 * wA * wB;
    feats[p * CDIM + c] = r;
}

// ---------------------------------------------------------------------------
// Kernel B: fused warp-MLP -> grid_sample -> render-MLP per (batch, pixel).
// One thread per (b, pixel). h[32]/z[32] live in VGPRs; all loops touching
// them are fully unrolled (no runtime register indexing). Weight addresses
// are wave-uniform -> scalar loads, v_fmac with SGPR operand.
// ---------------------------------------------------------------------------
__global__ __launch_bounds__(256) void fused_kernel(
    const float* __restrict__ t, const float* __restrict__ xy_basis,
    const float* __restrict__ w_in, const float* __restrict__ b_in,
    const float* __restrict__ w_h, const float* __restrict__ b_h,
    const float* __restrict__ ln_g, const float* __restrict__ ln_b,
    const float* __restrict__ w_out, const float* __restrict__ b_out,
    const float* __restrict__ r_wh, const float* __restrict__ r_bh,
    const float* __restrict__ r_wo, const float* __restrict__ r_bo,
    const float* __restrict__ feats, float* __restrict__ out)
{
    int tid = blockIdx.x * 256 + threadIdx.x;
    int p = tid & (NPIX - 1);
    int b = tid >> 18;          // 262144 = 2^18 pixels per batch

    float2 xy = ((const float2*)xy_basis)[p];
    float gx = xy.x, gy = xy.y;
    float alpha = t[b] + 0.5f;

    float h[CDIM];
    #pragma unroll
    for (int c = 0; c < CDIM; c++)
        h[c] = fmaf(gx, w_in[c],
               fmaf(gy, w_in[CDIM + c],
               fmaf(alpha, w_in[2 * CDIM + c], b_in[c])));

    // ---- 3 warp layers: h = sin(LN(h @ W + b) * g + beta) ----
    #pragma unroll 1
    for (int l = 0; l < 3; l++) {
        const float4* W4 = (const float4*)(w_h + l * CDIM * CDIM);
        float acc[CDIM];
        #pragma unroll
        for (int c = 0; c < CDIM; c++) acc[c] = b_h[l * CDIM + c];
        #pragma unroll
        for (int k = 0; k < CDIM; k++) {
            float hk = h[k];
            #pragma unroll
            for (int q = 0; q < CDIM / 4; q++) {
                float4 w = W4[k * (CDIM / 4) + q];
                acc[q * 4 + 0] = fmaf(hk, w.x, acc[q * 4 + 0]);
                acc[q * 4 + 1] = fmaf(hk, w.y, acc[q * 4 + 1]);
                acc[q * 4 + 2] = fmaf(hk, w.z, acc[q * 4 + 2]);
                acc[q * 4 + 3] = fmaf(hk, w.w, acc[q * 4 + 3]);
            }
        }
        float mu = 0.f;
        #pragma unroll
        for (int c = 0; c < CDIM; c++) mu += acc[c];
        mu *= (1.0f / CDIM);
        float var = 0.f;
        #pragma unroll
        for (int c = 0; c < CDIM; c++) { float d = acc[c] - mu; var = fmaf(d, d, var); }
        var *= (1.0f / CDIM);
        float rs = rsqrtf(var + 1e-5f);
        #pragma unroll
        for (int c = 0; c < CDIM; c++)
            h[c] = __sinf(fmaf((acc[c] - mu) * rs, ln_g[l * CDIM + c], ln_b[l * CDIM + c]));
    }

    // ---- motion head -> sample grid ----
    float mx = b_out[0], my = b_out[1];
    #pragma unroll
    for (int k = 0; k < CDIM; k++) {
        mx = fmaf(h[k], w_out[k * 2 + 0], mx);
        my = fmaf(h[k], w_out[k * 2 + 1], my);
    }
    float gridx = fmaf(mx, 0.1f, gx);
    float gridy = fmaf(my, 0.1f, gy);

    // ---- grid_sample (bilinear, zero pad) ----
    float ix = ((gridx + 1.0f) * XDIM - 1.0f) * 0.5f;
    float iy = ((gridy + 1.0f) * XDIM - 1.0f) * 0.5f;
    float x0f = floorf(ix), y0f = floorf(iy);
    float wx1 = ix - x0f, wy1 = iy - y0f;

    float z[CDIM];
    #pragma unroll
    for (int c = 0; c < CDIM; c++) z[c] = 0.f;

    #pragma unroll
    for (int corner = 0; corner < 4; corner++) {
        float xf = x0f + (float)(corner & 1);
        float yf = y0f + (float)(corner >> 1);
        float w = ((corner & 1) ? wx1 : 1.f - wx1) * ((corner >> 1) ? wy1 : 1.f - wy1);
        bool valid = (xf >= 0.f) && (xf <= (float)(XDIM - 1)) &&
                     (yf >= 0.f) && (yf <= (float)(XDIM - 1));
        if (!valid) w = 0.f;
        int xi = (int)fminf(fmaxf(xf, 0.f), (float)(XDIM - 1));
        int yi = (int)fminf(fmaxf(yf, 0.f), (float)(XDIM - 1));
        const float4* fp = (const float4*)(feats + (yi * XDIM + xi) * CDIM);
        #pragma unroll
        for (int q = 0; q < CDIM / 4; q++) {
            float4 v = fp[q];
            z[q * 4 + 0] = fmaf(w, v.x, z[q * 4 + 0]);
            z[q * 4 + 1] = fmaf(w, v.y, z[q * 4 + 1]);
            z[q * 4 + 2] = fmaf(w, v.z, z[q * 4 + 2]);
            z[q * 4 + 3] = fmaf(w, v.w, z[q * 4 + 3]);
        }
    }

    // ---- 3 render layers: z = relu(z @ W + b) ----
    #pragma unroll 1
    for (int l = 0; l < 3; l++) {
        const float4* W4 = (const float4*)(r_wh + l * CDIM * CDIM);
        float acc[CDIM];
        #pragma unroll
        for (int c = 0; c < CDIM; c++) acc[c] = r_bh[l * CDIM + c];
        #pragma unroll
        for (int k = 0; k < CDIM; k++) {
            float zk = z[k];
            #pragma unroll
            for (int q = 0; q < CDIM / 4; q++) {
                float4 w = W4[k * (CDIM / 4) + q];
                acc[q * 4 + 0] = fmaf(zk, w.x, acc[q * 4 + 0]);
                acc[q * 4 + 1] = fmaf(zk, w.y, acc[q * 4 + 1]);
                acc[q * 4 + 2] = fmaf(zk, w.z, acc[q * 4 + 2]);
                acc[q * 4 + 3] = fmaf(zk, w.w, acc[q * 4 + 3]);
            }
        }
        #pragma unroll
        for (int c = 0; c < CDIM; c++) z[c] = fmaxf(acc[c], 0.f);
    }

    float o = r_bo[0];
    #pragma unroll
    for (int k = 0; k < CDIM; k++) o = fmaf(z[k], r_wo[k], o);
    out[tid] = (o >= 0.f) ? o : 0.001f * o;
}

extern "C" void kernel_launch(void* const* d_in, const int* in_sizes, int n_in,
                              void* d_out, int out_size, void* d_ws, size_t ws_size,
                              hipStream_t stream) {
    const float* t        = (const float*)d_in[0];
    const float* data     = (const float*)d_in[1];
    const float* lerp_w   = (const float*)d_in[2];
    const float* xy_basis = (const float*)d_in[3];
    const float* w_in     = (const float*)d_in[4];
    const float* b_in     = (const float*)d_in[5];
    const float* w_h      = (const float*)d_in[6];
    const float* b_h      = (const float*)d_in[7];
    const float* ln_g     = (const float*)d_in[8];
    const float* ln_b     = (const float*)d_in[9];
    const float* w_out    = (const float*)d_in[10];
    const float* b_out    = (const float*)d_in[11];
    const float* r_wh     = (const float*)d_in[12];
    const float* r_bh     = (const float*)d_in[13];
    const float* r_wo     = (const float*)d_in[14];
    const float* r_bo     = (const float*)d_in[15];
    const int* x0 = (const int*)d_in[16];
    const int* y0 = (const int*)d_in[17];
    const int* x1 = (const int*)d_in[18];
    const int* y1 = (const int*)d_in[19];

    float* feats = (float*)d_ws;               // 512*512*32*4 = 33.5 MB scratch
    float* out = (float*)d_out;

    feats_kernel<<<(NPIX * CDIM) / 256, 256, 0, stream>>>(data, lerp_w, x0, y0, x1, y1, feats);
    fused_kernel<<<(8 * NPIX) / 256, 256, 0, stream>>>(
        t, xy_basis, w_in, b_in, w_h, b_h, ln_g, ln_b,
        w_out, b_out, r_wh, r_bh, r_wo, r_bo, feats, out);
}

// Round 2
// 294.123 us; speedup vs baseline: 1.4655x; 1.4655x over previous
//
#include <hip/hip_runtime.h>

#define XDIM 512
#define CDIM 32
#define NPIX (XDIM * XDIM)
#define NB 8

typedef short bf16x8 __attribute__((ext_vector_type(8)));   // 8 bf16 as i16 bits
typedef float f32x4 __attribute__((ext_vector_type(4)));

#define FEATS_BYTES (NPIX * CDIM * 4)          // 33554432
// afrag: [6 layers][2 outch-tiles][2 hi/lo][64 lanes][8 elems] ushort
#define AFRAG_ELEMS (6 * 2 * 2 * 64 * 8)

__device__ __forceinline__ short f2bf(float v) {
    __bf16 b = (__bf16)v;
    return __builtin_bit_cast(short, b);
}
__device__ __forceinline__ float bfup(short s) {
    return (float)__builtin_bit_cast(__bf16, s);
}

// ---------------------------------------------------------------------------
// Prep: split weights into bf16 hi/lo laid out in exact A-fragment order.
// A = W^T (rows = out-channel m, cols = in-channel k). 16x16x32 A-frag:
// lane l holds row m = l&15 (+16*tile), k = 8*(l>>4) + j, j=0..7.
// ---------------------------------------------------------------------------
__global__ __launch_bounds__(64) void wprep_kernel(
    const float* __restrict__ w_h, const float* __restrict__ r_wh,
    unsigned short* __restrict__ afrag)
{
    int L = blockIdx.x >> 1;      // 0..5
    int tile = blockIdx.x & 1;    // out-channel half
    int l = threadIdx.x;          // lane
    const float* W = (L < 3) ? (w_h + L * CDIM * CDIM) : (r_wh + (L - 3) * CDIM * CDIM);
    int m = tile * 16 + (l & 15);
    int kb = 8 * (l >> 4);
    unsigned short* dh = afrag + (((L * 2 + tile) * 2 + 0) * 64 + l) * 8;
    unsigned short* dl = afrag + (((L * 2 + tile) * 2 + 1) * 64 + l) * 8;
    for (int j = 0; j < 8; j++) {
        float v = W[(kb + j) * CDIM + m];   // W[k][m]
        short hi = f2bf(v);
        short lo = f2bf(v - bfup(hi));
        dh[j] = (unsigned short)hi;
        dl[j] = (unsigned short)lo;
    }
}

// ---------------------------------------------------------------------------
// Kernel A: batch-independent bilinear feature image (unchanged from R1).
// ---------------------------------------------------------------------------
__global__ __launch_bounds__(256) void feats_kernel(
    const float* __restrict__ data, const float* __restrict__ lerp_w,
    const int* __restrict__ x0, const int* __restrict__ y0,
    const int* __restrict__ x1, const int* __restrict__ y1,
    float* __restrict__ feats)
{
    int tid = blockIdx.x * 256 + threadIdx.x;
    int p = tid >> 5;
    int c = tid & 31;
    if (p >= NPIX) return;
    float wA = lerp_w[p * 2 + 0];
    float wB = lerp_w[p * 2 + 1];
    int xa = x0[p], ya = y0[p], xb = x1[p], yb = y1[p];
    float v00 = data[(ya * XDIM + xa) * CDIM + c];
    float v01 = data[(ya * XDIM + xb) * CDIM + c];
    float v10 = data[(yb * XDIM + xa) * CDIM + c];
    float v11 = data[(yb * XDIM + xb) * CDIM + c];
    float r = v00 * (1.f - wA) * (1.f - wB) + v01 * wA * (1.f - wB)
            + v10 * (1.f - wA) * wB + v11 * wA * wB;
    feats[p * CDIM + c] = r;
}

// ---------------------------------------------------------------------------
// Fused MFMA kernel. One wave = 32 pixels of one batch.
// Activations live as cur[j][e] = h[k = 8q+e] of pixel (pbase + 16j + n),
// n = lane&15, q = lane>>4. (B-frag layout of 16x16x32: col n = lane&15,
// k = 8*(lane>>4)+e.) MFMA output D: col n = lane&15 (pixel), row =
// (lane>>4)*4 + reg (channel 16i + 4q + reg for out-tile i). [m89-verified]
// ---------------------------------------------------------------------------
__device__ __forceinline__ void build_frag(const float v[8], bf16x8& hi, bf16x8& lo) {
    #pragma unroll
    for (int e = 0; e < 8; e++) {
        short h = f2bf(v[e]);
        hi[e] = h;
        lo[e] = f2bf(v[e] - bfup(h));
    }
}

__device__ __forceinline__ void mlp_matmul(
    const unsigned short* __restrict__ afrag, int L, int lane,
    const bf16x8 bh[2], const bf16x8 bl[2], f32x4 acc[2][2])
{
    const bf16x8* ap = (const bf16x8*)afrag;
    #pragma unroll
    for (int i = 0; i < 2; i++) {
        bf16x8 ah = ap[((L * 2 + i) * 2 + 0) * 64 + lane];
        bf16x8 al = ap[((L * 2 + i) * 2 + 1) * 64 + lane];
        #pragma unroll
        for (int j = 0; j < 2; j++) {
            f32x4 a = {0.f, 0.f, 0.f, 0.f};
            a = __builtin_amdgcn_mfma_f32_16x16x32_bf16(al, bh[j], a, 0, 0, 0);
            a = __builtin_amdgcn_mfma_f32_16x16x32_bf16(ah, bl[j], a, 0, 0, 0);
            a = __builtin_amdgcn_mfma_f32_16x16x32_bf16(ah, bh[j], a, 0, 0, 0);
            acc[i][j] = a;
        }
    }
}

// Relayout D->(next) B: target lane (n,q) needs channels 8q..8q+7 = quads
// {2q, 2q+1}; quad g lives as s[g>>2][reg] on lane (n | ((g&3)<<4)).
__device__ __forceinline__ void repack(const float s0[4], const float s1[4],
                                       int n, int q, float o[8])
{
    int src1 = n | (((2 * q) & 3) << 4);
    int src2 = n | (((2 * q + 1) & 3) << 4);
    bool low = (q < 2);
    #pragma unroll
    for (int r = 0; r < 4; r++) {
        float a0 = __shfl(s0[r], src1, 64);
        float a1 = __shfl(s1[r], src1, 64);
        o[r] = low ? a0 : a1;
        float c0 = __shfl(s0[r], src2, 64);
        float c1 = __shfl(s1[r], src2, 64);
        o[4 + r] = low ? c0 : c1;
    }
}

__global__ __launch_bounds__(256) void fused_mfma_kernel(
    const float* __restrict__ t, const float* __restrict__ xy_basis,
    const float* __restrict__ w_in, const float* __restrict__ b_in,
    const float* __restrict__ b_h,
    const float* __restrict__ ln_g, const float* __restrict__ ln_b,
    const float* __restrict__ w_out, const float* __restrict__ b_out,
    const float* __restrict__ r_bh,
    const float* __restrict__ r_wo, const float* __restrict__ r_bo,
    const float* __restrict__ feats, const unsigned short* __restrict__ afrag,
    float* __restrict__ out)
{
    int lane = threadIdx.x & 63;
    int wid = (blockIdx.x * 256 + threadIdx.x) >> 6;
    int item = wid * 32;
    int b = item >> 18;              // NPIX = 2^18
    int pbase = item & (NPIX - 1);
    int n = lane & 15, q = lane >> 4;
    int kb = 8 * q;

    float alpha = t[b] + 0.5f;
    int p0 = pbase + n, p1 = pbase + 16 + n;
    float2 xy0 = ((const float2*)xy_basis)[p0];
    float2 xy1 = ((const float2*)xy_basis)[p1];

    // ---- input layer: h0[k] for k = kb..kb+7, both pixel halves ----
    float r0[8], r1[8], r2[8], bi[8];
    *(f32x4*)&r0[0] = *(const f32x4*)(w_in + kb);
    *(f32x4*)&r0[4] = *(const f32x4*)(w_in + kb + 4);
    *(f32x4*)&r1[0] = *(const f32x4*)(w_in + CDIM + kb);
    *(f32x4*)&r1[4] = *(const f32x4*)(w_in + CDIM + kb + 4);
    *(f32x4*)&r2[0] = *(const f32x4*)(w_in + 2 * CDIM + kb);
    *(f32x4*)&r2[4] = *(const f32x4*)(w_in + 2 * CDIM + kb + 4);
    *(f32x4*)&bi[0] = *(const f32x4*)(b_in + kb);
    *(f32x4*)&bi[4] = *(const f32x4*)(b_in + kb + 4);

    float cur[2][8];
    #pragma unroll
    for (int e = 0; e < 8; e++) {
        cur[0][e] = fmaf(xy0.x, r0[e], fmaf(xy0.y, r1[e], fmaf(alpha, r2[e], bi[e])));
        cur[1][e] = fmaf(xy1.x, r0[e], fmaf(xy1.y, r1[e], fmaf(alpha, r2[e], bi[e])));
    }

    float sv[2][2][4];   // [out-tile i][pixel-half j][reg]
    f32x4 acc[2][2];

    // ---- 3 warp layers: sin(LN(h@W + b)) ----
    #pragma unroll 1
    for (int L = 0; L < 3; L++) {
        bf16x8 bh[2], bl[2];
        build_frag(cur[0], bh[0], bl[0]);
        build_frag(cur[1], bh[1], bl[1]);
        mlp_matmul(afrag, L, lane, bh, bl, acc);

        f32x4 bia0 = *(const f32x4*)(b_h + L * CDIM + 4 * q);
        f32x4 bia1 = *(const f32x4*)(b_h + L * CDIM + 16 + 4 * q);
        f32x4 g0 = *(const f32x4*)(ln_g + L * CDIM + 4 * q);
        f32x4 g1 = *(const f32x4*)(ln_g + L * CDIM + 16 + 4 * q);
        f32x4 be0 = *(const f32x4*)(ln_b + L * CDIM + 4 * q);
        f32x4 be1 = *(const f32x4*)(ln_b + L * CDIM + 16 + 4 * q);

        #pragma unroll
        for (int j = 0; j < 2; j++) {
            float sum = 0.f, sq = 0.f;
            #pragma unroll
            for (int i = 0; i < 2; i++)
                #pragma unroll
                for (int r = 0; r < 4; r++) {
                    float v = acc[i][j][r] + ((i == 0) ? bia0[r] : bia1[r]);
                    sv[i][j][r] = v;
                    sum += v;
                    sq = fmaf(v, v, sq);
                }
            sum += __shfl_xor(sum, 16, 64); sum += __shfl_xor(sum, 32, 64);
            sq  += __shfl_xor(sq , 16, 64); sq  += __shfl_xor(sq , 32, 64);
            float mu = sum * (1.f / 32.f);
            float var = fmaf(-mu, mu, sq * (1.f / 32.f));
            float rs = rsqrtf(var + 1e-5f);
            #pragma unroll
            for (int i = 0; i < 2; i++)
                #pragma unroll
                for (int r = 0; r < 4; r++) {
                    float gg = (i == 0) ? g0[r] : g1[r];
                    float bb = (i == 0) ? be0[r] : be1[r];
                    sv[i][j][r] = __sinf(fmaf((sv[i][j][r] - mu) * rs, gg, bb));
                }
        }
        if (L < 2) {
            repack(sv[0][0], sv[1][0], n, q, cur[0]);
            repack(sv[0][1], sv[1][1], n, q, cur[1]);
        }
    }

    // ---- motion head: m = h @ w_out + b_out, grid = 0.1*m + xy ----
    f32x4 wo00 = *(const f32x4*)(w_out + 8 * q);          // ch 4q..4q+1 (x,y pairs)
    f32x4 wo01 = *(const f32x4*)(w_out + 8 * q + 4);      // ch 4q+2..4q+3
    f32x4 wo10 = *(const f32x4*)(w_out + 2 * 16 + 8 * q);       // ch 16+4q..
    f32x4 wo11 = *(const f32x4*)(w_out + 2 * 16 + 8 * q + 4);
    float mx[2] = {0.f, 0.f}, my[2] = {0.f, 0.f};
    #pragma unroll
    for (int j = 0; j < 2; j++) {
        #pragma unroll
        for (int r = 0; r < 4; r++) {
            float wx0 = (r < 2) ? wo00[2 * r] : wo01[2 * (r - 2)];
            float wy0 = (r < 2) ? wo00[2 * r + 1] : wo01[2 * (r - 2) + 1];
            float wx1 = (r < 2) ? wo10[2 * r] : wo11[2 * (r - 2)];
            float wy1 = (r < 2) ? wo10[2 * r + 1] : wo11[2 * (r - 2) + 1];
            mx[j] = fmaf(sv[0][j][r], wx0, fmaf(sv[1][j][r], wx1, mx[j]));
            my[j] = fmaf(sv[0][j][r], wy0, fmaf(sv[1][j][r], wy1, my[j]));
        }
        mx[j] += __shfl_xor(mx[j], 16, 64); mx[j] += __shfl_xor(mx[j], 32, 64);
        my[j] += __shfl_xor(my[j], 16, 64); my[j] += __shfl_xor(my[j], 32, 64);
    }
    float bo0 = b_out[0], bo1 = b_out[1];
    float gxp[2] = {xy0.x, xy1.x}, gyp[2] = {xy0.y, xy1.y};

    // ---- grid sample: gather channels kb..kb+7 of each pixel half ----
    #pragma unroll
    for (int j = 0; j < 2; j++) {
        float gridx = fmaf(mx[j] + bo0, 0.1f, gxp[j]);
        float gridy = fmaf(my[j] + bo1, 0.1f, gyp[j]);
        float ix = ((gridx + 1.0f) * (float)XDIM - 1.0f) * 0.5f;
        float iy = ((gridy + 1.0f) * (float)XDIM - 1.0f) * 0.5f;
        float x0f = floorf(ix), y0f = floorf(iy);
        float wx1 = ix - x0f, wy1 = iy - y0f;
        float fv[8];
        #pragma unroll
        for (int e = 0; e < 8; e++) fv[e] = 0.f;
        #pragma unroll
        for (int corner = 0; corner < 4; corner++) {
            float xf = x0f + (float)(corner & 1);
            float yf = y0f + (float)(corner >> 1);
            float w = ((corner & 1) ? wx1 : 1.f - wx1) * ((corner >> 1) ? wy1 : 1.f - wy1);
            bool valid = (xf >= 0.f) && (xf <= (float)(XDIM - 1)) &&
                         (yf >= 0.f) && (yf <= (float)(XDIM - 1));
            if (!valid) w = 0.f;
            int xi = (int)fminf(fmaxf(xf, 0.f), (float)(XDIM - 1));
            int yi = (int)fminf(fmaxf(yf, 0.f), (float)(XDIM - 1));
            const f32x4* fp = (const f32x4*)(feats + (yi * XDIM + xi) * CDIM + kb);
            f32x4 v0 = fp[0], v1 = fp[1];
            #pragma unroll
            for (int e = 0; e < 4; e++) {
                fv[e]     = fmaf(w, v0[e], fv[e]);
                fv[4 + e] = fmaf(w, v1[e], fv[4 + e]);
            }
        }
        #pragma unroll
        for (int e = 0; e < 8; e++) cur[j][e] = fv[e];
    }

    // ---- 3 render layers: relu(z@W + b) ----
    #pragma unroll 1
    for (int L = 3; L < 6; L++) {
        bf16x8 bh[2], bl[2];
        build_frag(cur[0], bh[0], bl[0]);
        build_frag(cur[1], bh[1], bl[1]);
        mlp_matmul(afrag, L, lane, bh, bl, acc);

        f32x4 bia0 = *(const f32x4*)(r_bh + (L - 3) * CDIM + 4 * q);
        f32x4 bia1 = *(const f32x4*)(r_bh + (L - 3) * CDIM + 16 + 4 * q);
        #pragma unroll
        for (int j = 0; j < 2; j++)
            #pragma unroll
            for (int i = 0; i < 2; i++)
                #pragma unroll
                for (int r = 0; r < 4; r++) {
                    float v = acc[i][j][r] + ((i == 0) ? bia0[r] : bia1[r]);
                    sv[i][j][r] = fmaxf(v, 0.f);
                }
        if (L < 5) {
            repack(sv[0][0], sv[1][0], n, q, cur[0]);
            repack(sv[0][1], sv[1][1], n, q, cur[1]);
        }
    }

    // ---- output head ----
    f32x4 wz0 = *(const f32x4*)(r_wo + 4 * q);
    f32x4 wz1 = *(const f32x4*)(r_wo + 16 + 4 * q);
    float rbo = r_bo[0];
    float o[2] = {0.f, 0.f};
    #pragma unroll
    for (int j = 0; j < 2; j++) {
        #pragma unroll
        for (int r = 0; r < 4; r++)
            o[j] = fmaf(sv[0][j][r], wz0[r], fmaf(sv[1][j][r], wz1[r], o[j]));
        o[j] += __shfl_xor(o[j], 16, 64); o[j] += __shfl_xor(o[j], 32, 64);
        o[j] += rbo;
        o[j] = (o[j] >= 0.f) ? o[j] : 0.001f * o[j];
    }
    if (lane < 16)
        out[b * NPIX + pbase + n] = o[0];
    else if (lane < 32)
        out[b * NPIX + pbase + 16 + n] = o[1];
}

extern "C" void kernel_launch(void* const* d_in, const int* in_sizes, int n_in,
                              void* d_out, int out_size, void* d_ws, size_t ws_size,
                              hipStream_t stream) {
    const float* t        = (const float*)d_in[0];
    const float* data     = (const float*)d_in[1];
    const float* lerp_w   = (const float*)d_in[2];
    const float* xy_basis = (const float*)d_in[3];
    const float* w_in     = (const float*)d_in[4];
    const float* b_in     = (const float*)d_in[5];
    const float* w_h      = (const float*)d_in[6];
    const float* b_h      = (const float*)d_in[7];
    const float* ln_g     = (const float*)d_in[8];
    const float* ln_b     = (const float*)d_in[9];
    const float* w_out    = (const float*)d_in[10];
    const float* b_out    = (const float*)d_in[11];
    const float* r_wh     = (const float*)d_in[12];
    const float* r_bh     = (const float*)d_in[13];
    const float* r_wo     = (const float*)d_in[14];
    const float* r_bo     = (const float*)d_in[15];
    const int* x0 = (const int*)d_in[16];
    const int* y0 = (const int*)d_in[17];
    const int* x1 = (const int*)d_in[18];
    const int* y1 = (const int*)d_in[19];

    float* feats = (float*)d_ws;
    unsigned short* afrag = (unsigned short*)((char*)d_ws + FEATS_BYTES);
    float* out = (float*)d_out;

    wprep_kernel<<<12, 64, 0, stream>>>(w_h, r_wh, afrag);
    feats_kernel<<<(NPIX * CDIM) / 256, 256, 0, stream>>>(data, lerp_w, x0, y0, x1, y1, feats);
    fused_mfma_kernel<<<(NB * NPIX) / 128, 256, 0, stream>>>(
        t, xy_basis, w_in, b_in, b_h, ln_g, ln_b, w_out, b_out,
        r_bh, r_wo, r_bo, feats, afrag, out);
}